// Round 1
// baseline (170.296 us; speedup 1.0000x reference)
//
#include <hip/hip_runtime.h>

#define N      4096
#define NIN    64
#define NHID   32
#define NOUT   64
#define NHEADS 8
#define H_SP   6
#define D_INT  32
#define MAXDEG 128
#define NPB    4      // nodes per block in K1
#define NPB2   2      // nodes per block in K2 (halves Wout L2 re-read)
#define ALPHA  0.2f

// popc(mask & lanemask_lt) — prefix population count for wave64 ballots
__device__ __forceinline__ int mbcnt64(unsigned long long m) {
    return __builtin_amdgcn_mbcnt_hi((unsigned)(m >> 32),
           __builtin_amdgcn_mbcnt_lo((unsigned)m, 0u));
}

// ---------------------------------------------------------------------------
// K1 (fused proj + csr), 4 nodes per block, 1024 blocks.
//  - xs transposed in LDS: one ds_read_b128 broadcast feeds all 4 node accs
//    (was 4x ds_read_b32 per c).
//  - csr compaction via ballot + mbcnt prefix (dependent chain ~3 ops, was a
//    6-step serialized shfl_up scan). Within-float4 output order is
//    component-major (x of all lanes, then y, ...) — set semantics unchanged.
// ---------------------------------------------------------------------------
__global__ __launch_bounds__(256) void k_fused1(
    const float* __restrict__ x, const float* __restrict__ ie,
    const float4* __restrict__ adj4,
    const float* __restrict__ Wsp, const float* __restrict__ asp,
    const float* __restrict__ Wint, const float* __restrict__ aint,
    float* __restrict__ Wh_t, float* __restrict__ src, float* __restrict__ dst_t,
    int* __restrict__ col, int* __restrict__ deg)
{
    const int nb   = blockIdx.x * NPB;
    const int tid  = threadIdx.x;
    const int wv   = tid >> 6, lane = tid & 63;
    const int h    = tid >> 5, f    = tid & 31;

    __shared__ float xs_t[NIN][NPB];     // transposed x tile: [col][node]
    __shared__ float ies[NPB][D_INT];

    xs_t[tid & 63][tid >> 6] = x[nb * NIN + tid];
    if (tid < NPB * D_INT) ies[tid >> 5][tid & 31] = ie[nb * D_INT + tid];
    __syncthreads();

    // --- projection: 8 head-groups x 32 lanes, 4 nodes each ---
    const float* W = (h < H_SP) ? (Wsp + h * NIN * NHID)
                                : (Wint + (h - H_SP) * NIN * NHID);
    float acc[NPB] = {0.f, 0.f, 0.f, 0.f};
#pragma unroll
    for (int c = 0; c < NIN; ++c) {
        const float wval = W[c * NHID + f];
        const float4 xv  = *(const float4*)&xs_t[c][0];   // broadcast b128
        acc[0] += xv.x * wval; acc[1] += xv.y * wval;
        acc[2] += xv.z * wval; acc[3] += xv.w * wval;
    }
#pragma unroll
    for (int m = 0; m < NPB; ++m)
        Wh_t[(size_t)(nb + m) * 256 + tid] = acc[m];   // coalesced 1 KB stores

    // --- rank-1 score halves (2*NHID == 2*D_INT == 64) ---
    const float a1v = (h < H_SP) ? asp[h * 64 + f]      : aint[(h - H_SP) * 64 + f];
    const float a2v = (h < H_SP) ? asp[h * 64 + 32 + f] : aint[(h - H_SP) * 64 + 32 + f];
#pragma unroll
    for (int m = 0; m < NPB; ++m) {
        const float b = (h < H_SP) ? acc[m] : ies[m][f];
        float s1 = b * a1v, s2 = b * a2v;
#pragma unroll
        for (int mm = 16; mm >= 1; mm >>= 1) {
            s1 += __shfl_xor(s1, mm);
            s2 += __shfl_xor(s2, mm);
        }
        if (f == 0) { src[h * N + nb + m] = s1; dst_t[(nb + m) * 8 + h] = s2; }
    }

    // --- csr: wave wv compacts row nb+wv via ballots (no serial scan) ---
    const int r = nb + wv;
    const float4* row = adj4 + (size_t)r * (N / 4);
    int cnt = 0;
#pragma unroll 4
    for (int t = 0; t < 16; ++t) {
        float4 v = row[t * 64 + lane];
        unsigned long long bx = __ballot(v.x > 0.f);
        unsigned long long by = __ballot(v.y > 0.f);
        unsigned long long bz = __ballot(v.z > 0.f);
        unsigned long long bw = __ballot(v.w > 0.f);
        const int tx = __popcll(bx), ty = __popcll(by);
        const int tz = __popcll(bz), tw = __popcll(bw);
        const int idx0 = (t * 64 + lane) * 4;
        const int px = cnt + mbcnt64(bx);
        const int py = cnt + tx + mbcnt64(by);
        const int pz = cnt + tx + ty + mbcnt64(bz);
        const int pw = cnt + tx + ty + tz + mbcnt64(bw);
        if (v.x > 0.f && px < MAXDEG) col[r * MAXDEG + px] = idx0;
        if (v.y > 0.f && py < MAXDEG) col[r * MAXDEG + py] = idx0 + 1;
        if (v.z > 0.f && pz < MAXDEG) col[r * MAXDEG + pz] = idx0 + 2;
        if (v.w > 0.f && pw < MAXDEG) col[r * MAXDEG + pw] = idx0 + 3;
        cnt += tx + ty + tz + tw;
    }
    if (lane == 0) deg[r] = (cnt < MAXDEG) ? cnt : MAXDEG;
}

// ---------------------------------------------------------------------------
// K2 (fused attn1 + Who): TWO destination nodes per block, 2048 blocks.
// Wout is read once per block and feeds both rows (L2 traffic 268->134 MB);
// dual-row fused gather keeps 16 independent loads in flight.
// ---------------------------------------------------------------------------
__global__ __launch_bounds__(256) void k_attn1who(
    const int* __restrict__ col, const int* __restrict__ deg,
    const float* __restrict__ Wh_t, const float* __restrict__ src,
    const float* __restrict__ dst_t, const float* __restrict__ Wout,
    const float* __restrict__ aout,
    float* __restrict__ Who, float* __restrict__ o1, float* __restrict__ o2)
{
    const int r0  = blockIdx.x * NPB2;
    const int tid = threadIdx.x;
    const int h   = tid >> 5, lane = tid & 31;

    __shared__ int   cs[NPB2][MAXDEG];
    __shared__ float w[NPB2][NHEADS][MAXDEG];
    __shared__ float hs[NPB2][NHEADS * NHID];
    __shared__ float part[NPB2][4][NOUT];

    const int d0 = deg[r0], d1 = deg[r0 + 1];
    {
        const int m = tid >> 7, k = tid & 127;
        const int dm = m ? d1 : d0;
        cs[m][k] = (k < dm) ? col[(r0 + m) * MAXDEG + k] : 0;  // pad node 0 (w=0)
    }
    __syncthreads();

    // --- per-head sparse softmax, both rows ---
#pragma unroll
    for (int m = 0; m < NPB2; ++m) {
        const int dm = m ? d1 : d0;
        const float sr = src[h * N + r0 + m];
        float ev[4];
        float mx = -3.4e38f;
#pragma unroll
        for (int t = 0; t < 4; ++t) {
            const int k = lane + t * 32;
            float e = -3.4e38f;
            if (k < dm) {
                e = sr + dst_t[cs[m][k] * 8 + h];
                e = e > 0.f ? e : ALPHA * e;
            }
            ev[t] = e;
            mx = fmaxf(mx, e);
        }
#pragma unroll
        for (int mm = 16; mm >= 1; mm >>= 1) mx = fmaxf(mx, __shfl_xor(mx, mm));
        float sum = 0.f;
#pragma unroll
        for (int t = 0; t < 4; ++t) {
            const int k = lane + t * 32;
            float p = (k < dm) ? __expf(ev[t] - mx) : 0.f;
            ev[t] = p;
            sum += p;
        }
#pragma unroll
        for (int mm = 16; mm >= 1; mm >>= 1) sum += __shfl_xor(sum, mm);
        const float inv = 1.f / sum;
#pragma unroll
        for (int t = 0; t < 4; ++t) w[m][h][lane + t * 32] = ev[t] * inv;  // all 128, 0-pad
    }
    __syncthreads();

    // --- dual-row aggregation: 8-wide per row, branch-free ---
    const int d8a = (d0 + 7) & ~7, d8b = (d1 + 7) & ~7;
    const int d8m = d8a > d8b ? d8a : d8b;
    float a0 = 0.f, a1 = 0.f, c0 = 0.f, c1 = 0.f;
    for (int k = 0; k < d8m; k += 8) {
        int4   ja = *(const int4*)  &cs[0][k];
        int4   jA = *(const int4*)  &cs[0][k + 4];
        int4   jb = *(const int4*)  &cs[1][k];
        int4   jB = *(const int4*)  &cs[1][k + 4];
        float4 wa = *(const float4*)&w[0][h][k];
        float4 wA = *(const float4*)&w[0][h][k + 4];
        float4 wb = *(const float4*)&w[1][h][k];
        float4 wB = *(const float4*)&w[1][h][k + 4];
        a0 += wa.x * Wh_t[(size_t)ja.x * 256 + tid] + wa.y * Wh_t[(size_t)ja.y * 256 + tid]
            + wa.z * Wh_t[(size_t)ja.z * 256 + tid] + wa.w * Wh_t[(size_t)ja.w * 256 + tid];
        a1 += wA.x * Wh_t[(size_t)jA.x * 256 + tid] + wA.y * Wh_t[(size_t)jA.y * 256 + tid]
            + wA.z * Wh_t[(size_t)jA.z * 256 + tid] + wA.w * Wh_t[(size_t)jA.w * 256 + tid];
        c0 += wb.x * Wh_t[(size_t)jb.x * 256 + tid] + wb.y * Wh_t[(size_t)jb.y * 256 + tid]
            + wb.z * Wh_t[(size_t)jb.z * 256 + tid] + wb.w * Wh_t[(size_t)jb.w * 256 + tid];
        c1 += wB.x * Wh_t[(size_t)jB.x * 256 + tid] + wB.y * Wh_t[(size_t)jB.y * 256 + tid]
            + wB.z * Wh_t[(size_t)jB.z * 256 + tid] + wB.w * Wh_t[(size_t)jB.w * 256 + tid];
    }
    float av = a0 + a1; av = av > 0.f ? av : __expf(av) - 1.f;  // elu
    float cv = c0 + c1; cv = cv > 0.f ? cv : __expf(cv) - 1.f;
    hs[0][tid] = av;
    hs[1][tid] = cv;
    __syncthreads();

    // --- Who[r,:] = hrow @ W_out, Wout element shared by both rows ---
    const int fo = tid & 63, q = tid >> 6;
    float p0 = 0.f, p1 = 0.f;
#pragma unroll
    for (int c = q * 64; c < q * 64 + 64; ++c) {
        const float wv_ = Wout[c * NOUT + fo];
        p0 += hs[0][c] * wv_;
        p1 += hs[1][c] * wv_;
    }
    part[0][q][fo] = p0;
    part[1][q][fo] = p1;
    __syncthreads();

    if (tid < 128) {
        const int m = tid >> 6, fo2 = tid & 63;
        float who = part[m][0][fo2] + part[m][1][fo2] + part[m][2][fo2] + part[m][3][fo2];
        Who[(size_t)(r0 + m) * NOUT + fo2] = who;
        float v1 = who * aout[fo2];
        float v2 = who * aout[NOUT + fo2];
#pragma unroll
        for (int mm = 32; mm >= 1; mm >>= 1) {
            v1 += __shfl_xor(v1, mm);
            v2 += __shfl_xor(v2, mm);
        }
        if (fo2 == 0) { o1[r0 + m] = v1; o2[r0 + m] = v2; }
    }
}

// ---------------------------------------------------------------------------
// K3 (attn2): wave-per-row, sync-free, no LDS. 1024 blocks x 4 waves.
// Softmax in registers (d<=128 -> 2 slots/lane); neighbor (j,w) broadcast via
// readlane (uniform loop index -> sgpr-based coalesced 256 B gather).
// ---------------------------------------------------------------------------
__global__ __launch_bounds__(256) void k_attn2(
    const int* __restrict__ col, const int* __restrict__ deg,
    const float* __restrict__ Who, const float* __restrict__ o1,
    const float* __restrict__ o2, float* __restrict__ out)
{
    const int tid  = threadIdx.x;
    const int wv   = tid >> 6, lane = tid & 63;
    const int r    = blockIdx.x * 4 + wv;

    const int d  = deg[r];
    const int j0 = (lane < d)      ? col[r * MAXDEG + lane]      : 0;
    const int j1 = (lane + 64 < d) ? col[r * MAXDEG + 64 + lane] : 0;
    const float sr = o1[r];

    float e0 = -3.4e38f, e1 = -3.4e38f;
    if (lane < d)      { float e = sr + o2[j0]; e0 = e > 0.f ? e : ALPHA * e; }
    if (lane + 64 < d) { float e = sr + o2[j1]; e1 = e > 0.f ? e : ALPHA * e; }
    float mx = fmaxf(e0, e1);
#pragma unroll
    for (int m = 32; m >= 1; m >>= 1) mx = fmaxf(mx, __shfl_xor(mx, m));
    float p0 = (lane < d)      ? __expf(e0 - mx) : 0.f;
    float p1 = (lane + 64 < d) ? __expf(e1 - mx) : 0.f;
    float s = p0 + p1;
#pragma unroll
    for (int m = 32; m >= 1; m >>= 1) s += __shfl_xor(s, m);
    const float inv = 1.f / s;
    const float w0 = p0 * inv, w1 = p1 * inv;

    float acc = 0.f;
    const int dlo = d < 64 ? d : 64;
#pragma unroll 4
    for (int k = 0; k < dlo; ++k) {
        const int   j  = __builtin_amdgcn_readlane(j0, k);
        const float wt = __uint_as_float(
            __builtin_amdgcn_readlane(__float_as_uint(w0), k));
        acc += wt * Who[(size_t)j * NOUT + lane];
    }
#pragma unroll 2
    for (int k = 64; k < d; ++k) {
        const int   j  = __builtin_amdgcn_readlane(j1, k - 64);
        const float wt = __uint_as_float(
            __builtin_amdgcn_readlane(__float_as_uint(w1), k - 64));
        acc += wt * Who[(size_t)j * NOUT + lane];
    }
    out[(size_t)r * NOUT + lane] = tanhf(acc);
}

// ---------------------------------------------------------------------------
extern "C" void kernel_launch(void* const* d_in, const int* in_sizes, int n_in,
                              void* d_out, int out_size, void* d_ws, size_t ws_size,
                              hipStream_t stream) {
    const float* x    = (const float*)d_in[0];   // [4096,64]
    const float* adj  = (const float*)d_in[1];   // [4096,4096]
    const float* ie   = (const float*)d_in[2];   // [4096,32]
    const float* Wsp  = (const float*)d_in[3];   // [6,64,32]
    const float* asp  = (const float*)d_in[4];   // [6,64]
    const float* Wint = (const float*)d_in[5];   // [2,64,32]
    const float* aint = (const float*)d_in[6];   // [2,64]
    const float* Wout = (const float*)d_in[7];   // [256,64]
    const float* aout = (const float*)d_in[8];   // [128]
    float* out = (float*)d_out;                  // [4096,64]

    float* ws    = (float*)d_ws;
    float* Wh_t  = ws;                    // [4096][256]  node-major
    float* src   = Wh_t + 1048576;        // [8][4096]
    float* dst_t = src  + 32768;          // [4096][8]
    float* Who   = dst_t + 32768;         // [4096][64]
    float* o1    = Who  + 262144;         // [4096]
    float* o2    = o1   + 4096;           // [4096]
    int*   col   = (int*)(o2 + 4096);     // [4096][128]
    int*   deg   = col + 4096 * MAXDEG;   // [4096]

    k_fused1  <<<N / NPB,  256, 0, stream>>>(x, ie, (const float4*)adj, Wsp, asp,
                                             Wint, aint, Wh_t, src, dst_t, col, deg);
    k_attn1who<<<N / NPB2, 256, 0, stream>>>(col, deg, Wh_t, src, dst_t, Wout, aout,
                                             Who, o1, o2);
    k_attn2   <<<N / 4,    256, 0, stream>>>(col, deg, Who, o1, o2, out);
}

// Round 2
// 159.041 us; speedup vs baseline: 1.0708x; 1.0708x over previous
//
#include <hip/hip_runtime.h>

#define N      4096
#define NIN    64
#define NHID   32
#define NOUT   64
#define NHEADS 8
#define H_SP   6
#define D_INT  32
#define MAXDEG 128
#define NPB    4      // nodes per block in K1
#define ALPHA  0.2f

// popc(mask & lanemask_lt) — prefix population count for wave64 ballots
__device__ __forceinline__ int mbcnt64(unsigned long long m) {
    return __builtin_amdgcn_mbcnt_hi((unsigned)(m >> 32),
           __builtin_amdgcn_mbcnt_lo((unsigned)m, 0u));
}

// ---------------------------------------------------------------------------
// K1 (fused proj + csr), 4 nodes per block, 1024 blocks. (unchanged: <41us)
// ---------------------------------------------------------------------------
__global__ __launch_bounds__(256) void k_fused1(
    const float* __restrict__ x, const float* __restrict__ ie,
    const float4* __restrict__ adj4,
    const float* __restrict__ Wsp, const float* __restrict__ asp,
    const float* __restrict__ Wint, const float* __restrict__ aint,
    float* __restrict__ Wh_t, float* __restrict__ src, float* __restrict__ dst_t,
    int* __restrict__ col, int* __restrict__ deg)
{
    const int nb   = blockIdx.x * NPB;
    const int tid  = threadIdx.x;
    const int wv   = tid >> 6, lane = tid & 63;
    const int h    = tid >> 5, f    = tid & 31;

    __shared__ float xs_t[NIN][NPB];     // transposed x tile: [col][node]
    __shared__ float ies[NPB][D_INT];

    xs_t[tid & 63][tid >> 6] = x[nb * NIN + tid];
    if (tid < NPB * D_INT) ies[tid >> 5][tid & 31] = ie[nb * D_INT + tid];
    __syncthreads();

    // --- projection: 8 head-groups x 32 lanes, 4 nodes each ---
    const float* W = (h < H_SP) ? (Wsp + h * NIN * NHID)
                                : (Wint + (h - H_SP) * NIN * NHID);
    float acc[NPB] = {0.f, 0.f, 0.f, 0.f};
#pragma unroll
    for (int c = 0; c < NIN; ++c) {
        const float wval = W[c * NHID + f];
        const float4 xv  = *(const float4*)&xs_t[c][0];   // broadcast b128
        acc[0] += xv.x * wval; acc[1] += xv.y * wval;
        acc[2] += xv.z * wval; acc[3] += xv.w * wval;
    }
#pragma unroll
    for (int m = 0; m < NPB; ++m)
        Wh_t[(size_t)(nb + m) * 256 + tid] = acc[m];   // coalesced 1 KB stores

    // --- rank-1 score halves (2*NHID == 2*D_INT == 64) ---
    const float a1v = (h < H_SP) ? asp[h * 64 + f]      : aint[(h - H_SP) * 64 + f];
    const float a2v = (h < H_SP) ? asp[h * 64 + 32 + f] : aint[(h - H_SP) * 64 + 32 + f];
#pragma unroll
    for (int m = 0; m < NPB; ++m) {
        const float b = (h < H_SP) ? acc[m] : ies[m][f];
        float s1 = b * a1v, s2 = b * a2v;
#pragma unroll
        for (int mm = 16; mm >= 1; mm >>= 1) {
            s1 += __shfl_xor(s1, mm);
            s2 += __shfl_xor(s2, mm);
        }
        if (f == 0) { src[h * N + nb + m] = s1; dst_t[(nb + m) * 8 + h] = s2; }
    }

    // --- csr: wave wv compacts row nb+wv via ballots (no serial scan) ---
    const int r = nb + wv;
    const float4* row = adj4 + (size_t)r * (N / 4);
    int cnt = 0;
#pragma unroll 4
    for (int t = 0; t < 16; ++t) {
        float4 v = row[t * 64 + lane];
        unsigned long long bx = __ballot(v.x > 0.f);
        unsigned long long by = __ballot(v.y > 0.f);
        unsigned long long bz = __ballot(v.z > 0.f);
        unsigned long long bw = __ballot(v.w > 0.f);
        const int tx = __popcll(bx), ty = __popcll(by);
        const int tz = __popcll(bz), tw = __popcll(bw);
        const int idx0 = (t * 64 + lane) * 4;
        const int px = cnt + mbcnt64(bx);
        const int py = cnt + tx + mbcnt64(by);
        const int pz = cnt + tx + ty + mbcnt64(bz);
        const int pw = cnt + tx + ty + tz + mbcnt64(bw);
        if (v.x > 0.f && px < MAXDEG) col[r * MAXDEG + px] = idx0;
        if (v.y > 0.f && py < MAXDEG) col[r * MAXDEG + py] = idx0 + 1;
        if (v.z > 0.f && pz < MAXDEG) col[r * MAXDEG + pz] = idx0 + 2;
        if (v.w > 0.f && pw < MAXDEG) col[r * MAXDEG + pw] = idx0 + 3;
        cnt += tx + ty + tz + tw;
    }
    if (lane == 0) deg[r] = (cnt < MAXDEG) ? cnt : MAXDEG;
}

// ---------------------------------------------------------------------------
// K2 (fused attn1 + Who): ONE row per block, 4096 blocks (max latency chains).
//  - first 16 neighbor rows prefetched BEFORE softmax (loads depend only on
//    cs, ready after barrier 1) -> cold-load latency hides under softmax.
//  - 16-wide gather, 4 accumulators: 16 loads in flight per wave.
//  - __launch_bounds__(256,4): VGPR headroom for the 16-deep pipeline.
// ---------------------------------------------------------------------------
__global__ __launch_bounds__(256, 4) void k_attn1who(
    const int* __restrict__ col, const int* __restrict__ deg,
    const float* __restrict__ Wh_t, const float* __restrict__ src,
    const float* __restrict__ dst_t, const float* __restrict__ Wout,
    const float* __restrict__ aout,
    float* __restrict__ Who, float* __restrict__ o1, float* __restrict__ o2)
{
    const int r   = blockIdx.x;
    const int tid = threadIdx.x;
    const int h   = tid >> 5, lane = tid & 31;

    __shared__ __align__(16) int   cs[MAXDEG];
    __shared__ __align__(16) float w[NHEADS][MAXDEG];
    __shared__ float hs[NHEADS * NHID];
    __shared__ float part[4][NOUT];

    const int d = deg[r];
    if (tid < MAXDEG) cs[tid] = (tid < d) ? col[r * MAXDEG + tid] : 0;  // pad node 0 (w=0)
    __syncthreads();

    // --- prefetch neighbors 0..15 (w is zero-padded there, so always safe) ---
    const int4 ja = *(const int4*)&cs[0];
    const int4 jb = *(const int4*)&cs[4];
    const int4 jc = *(const int4*)&cs[8];
    const int4 jd = *(const int4*)&cs[12];
    const float g0  = Wh_t[(size_t)ja.x * 256 + tid];
    const float g1  = Wh_t[(size_t)ja.y * 256 + tid];
    const float g2  = Wh_t[(size_t)ja.z * 256 + tid];
    const float g3  = Wh_t[(size_t)ja.w * 256 + tid];
    const float g4  = Wh_t[(size_t)jb.x * 256 + tid];
    const float g5  = Wh_t[(size_t)jb.y * 256 + tid];
    const float g6  = Wh_t[(size_t)jb.z * 256 + tid];
    const float g7  = Wh_t[(size_t)jb.w * 256 + tid];
    const float g8  = Wh_t[(size_t)jc.x * 256 + tid];
    const float g9  = Wh_t[(size_t)jc.y * 256 + tid];
    const float g10 = Wh_t[(size_t)jc.z * 256 + tid];
    const float g11 = Wh_t[(size_t)jc.w * 256 + tid];
    const float g12 = Wh_t[(size_t)jd.x * 256 + tid];
    const float g13 = Wh_t[(size_t)jd.y * 256 + tid];
    const float g14 = Wh_t[(size_t)jd.z * 256 + tid];
    const float g15 = Wh_t[(size_t)jd.w * 256 + tid];

    // --- per-head sparse softmax (runs while prefetch is in flight) ---
    const float sr = src[h * N + r];
    float ev[4];
    float mx = -3.4e38f;
#pragma unroll
    for (int t = 0; t < 4; ++t) {
        const int k = lane + t * 32;
        float e = -3.4e38f;
        if (k < d) {
            e = sr + dst_t[cs[k] * 8 + h];
            e = e > 0.f ? e : ALPHA * e;
        }
        ev[t] = e;
        mx = fmaxf(mx, e);
    }
#pragma unroll
    for (int mm = 16; mm >= 1; mm >>= 1) mx = fmaxf(mx, __shfl_xor(mx, mm));

    float sum = 0.f;
#pragma unroll
    for (int t = 0; t < 4; ++t) {
        const int k = lane + t * 32;
        float p = (k < d) ? __expf(ev[t] - mx) : 0.f;
        ev[t] = p;
        sum += p;
    }
#pragma unroll
    for (int mm = 16; mm >= 1; mm >>= 1) sum += __shfl_xor(sum, mm);
    const float inv = 1.f / sum;
#pragma unroll
    for (int t = 0; t < 4; ++t)
        w[h][lane + t * 32] = ev[t] * inv;          // all 128 slots, 0 pad
    __syncthreads();

    // --- gather: iteration 0 consumes prefetched g; then 16-wide pipeline ---
    const float4 wa = *(const float4*)&w[h][0];
    const float4 wb = *(const float4*)&w[h][4];
    const float4 wc = *(const float4*)&w[h][8];
    const float4 wd = *(const float4*)&w[h][12];
    float acc0 = wa.x * g0  + wa.y * g1  + wa.z * g2  + wa.w * g3;
    float acc1 = wb.x * g4  + wb.y * g5  + wb.z * g6  + wb.w * g7;
    float acc2 = wc.x * g8  + wc.y * g9  + wc.z * g10 + wc.w * g11;
    float acc3 = wd.x * g12 + wd.y * g13 + wd.z * g14 + wd.w * g15;

    const int d16 = (d + 15) & ~15;
    for (int k = 16; k < d16; k += 16) {
        const int4 a = *(const int4*)&cs[k];
        const int4 b = *(const int4*)&cs[k + 4];
        const int4 c = *(const int4*)&cs[k + 8];
        const int4 e = *(const int4*)&cs[k + 12];
        const float4 w0 = *(const float4*)&w[h][k];
        const float4 w1 = *(const float4*)&w[h][k + 4];
        const float4 w2 = *(const float4*)&w[h][k + 8];
        const float4 w3 = *(const float4*)&w[h][k + 12];
        const float t0  = Wh_t[(size_t)a.x * 256 + tid];
        const float t1  = Wh_t[(size_t)a.y * 256 + tid];
        const float t2  = Wh_t[(size_t)a.z * 256 + tid];
        const float t3  = Wh_t[(size_t)a.w * 256 + tid];
        const float t4  = Wh_t[(size_t)b.x * 256 + tid];
        const float t5  = Wh_t[(size_t)b.y * 256 + tid];
        const float t6  = Wh_t[(size_t)b.z * 256 + tid];
        const float t7  = Wh_t[(size_t)b.w * 256 + tid];
        const float t8  = Wh_t[(size_t)c.x * 256 + tid];
        const float t9  = Wh_t[(size_t)c.y * 256 + tid];
        const float t10 = Wh_t[(size_t)c.z * 256 + tid];
        const float t11 = Wh_t[(size_t)c.w * 256 + tid];
        const float t12 = Wh_t[(size_t)e.x * 256 + tid];
        const float t13 = Wh_t[(size_t)e.y * 256 + tid];
        const float t14 = Wh_t[(size_t)e.z * 256 + tid];
        const float t15 = Wh_t[(size_t)e.w * 256 + tid];
        acc0 += w0.x * t0  + w0.y * t1  + w0.z * t2  + w0.w * t3;
        acc1 += w1.x * t4  + w1.y * t5  + w1.z * t6  + w1.w * t7;
        acc2 += w2.x * t8  + w2.y * t9  + w2.z * t10 + w2.w * t11;
        acc3 += w3.x * t12 + w3.y * t13 + w3.z * t14 + w3.w * t15;
    }
    float acc = (acc0 + acc1) + (acc2 + acc3);
    acc = acc > 0.f ? acc : __expf(acc) - 1.f;   // elu (concat heads)
    hs[tid] = acc;
    __syncthreads();

    // --- Who[r,:] = hrow @ W_out, split over 4 waves ---
    const int fo = tid & 63, q = tid >> 6;
    float p = 0.f;
#pragma unroll
    for (int c = q * 64; c < q * 64 + 64; ++c) p += hs[c] * Wout[c * NOUT + fo];
    part[q][fo] = p;
    __syncthreads();

    if (tid < 64) {
        float who = part[0][tid] + part[1][tid] + part[2][tid] + part[3][tid];
        Who[(size_t)r * NOUT + tid] = who;
        float v1 = who * aout[tid];
        float v2 = who * aout[NOUT + tid];
#pragma unroll
        for (int m = 32; m >= 1; m >>= 1) {
            v1 += __shfl_xor(v1, m);
            v2 += __shfl_xor(v2, m);
        }
        if (tid == 0) { o1[r] = v1; o2[r] = v2; }
    }
}

// ---------------------------------------------------------------------------
// K3 (attn2): wave-per-row, sync-free, no LDS. (unchanged: <41us)
// ---------------------------------------------------------------------------
__global__ __launch_bounds__(256) void k_attn2(
    const int* __restrict__ col, const int* __restrict__ deg,
    const float* __restrict__ Who, const float* __restrict__ o1,
    const float* __restrict__ o2, float* __restrict__ out)
{
    const int tid  = threadIdx.x;
    const int wv   = tid >> 6, lane = tid & 63;
    const int r    = blockIdx.x * 4 + wv;

    const int d  = deg[r];
    const int j0 = (lane < d)      ? col[r * MAXDEG + lane]      : 0;
    const int j1 = (lane + 64 < d) ? col[r * MAXDEG + 64 + lane] : 0;
    const float sr = o1[r];

    float e0 = -3.4e38f, e1 = -3.4e38f;
    if (lane < d)      { float e = sr + o2[j0]; e0 = e > 0.f ? e : ALPHA * e; }
    if (lane + 64 < d) { float e = sr + o2[j1]; e1 = e > 0.f ? e : ALPHA * e; }
    float mx = fmaxf(e0, e1);
#pragma unroll
    for (int m = 32; m >= 1; m >>= 1) mx = fmaxf(mx, __shfl_xor(mx, m));
    float p0 = (lane < d)      ? __expf(e0 - mx) : 0.f;
    float p1 = (lane + 64 < d) ? __expf(e1 - mx) : 0.f;
    float s = p0 + p1;
#pragma unroll
    for (int m = 32; m >= 1; m >>= 1) s += __shfl_xor(s, m);
    const float inv = 1.f / s;
    const float w0 = p0 * inv, w1 = p1 * inv;

    float acc = 0.f;
    const int dlo = d < 64 ? d : 64;
#pragma unroll 4
    for (int k = 0; k < dlo; ++k) {
        const int   j  = __builtin_amdgcn_readlane(j0, k);
        const float wt = __uint_as_float(
            __builtin_amdgcn_readlane(__float_as_uint(w0), k));
        acc += wt * Who[(size_t)j * NOUT + lane];
    }
#pragma unroll 2
    for (int k = 64; k < d; ++k) {
        const int   j  = __builtin_amdgcn_readlane(j1, k - 64);
        const float wt = __uint_as_float(
            __builtin_amdgcn_readlane(__float_as_uint(w1), k - 64));
        acc += wt * Who[(size_t)j * NOUT + lane];
    }
    out[(size_t)r * NOUT + lane] = tanhf(acc);
}

// ---------------------------------------------------------------------------
extern "C" void kernel_launch(void* const* d_in, const int* in_sizes, int n_in,
                              void* d_out, int out_size, void* d_ws, size_t ws_size,
                              hipStream_t stream) {
    const float* x    = (const float*)d_in[0];   // [4096,64]
    const float* adj  = (const float*)d_in[1];   // [4096,4096]
    const float* ie   = (const float*)d_in[2];   // [4096,32]
    const float* Wsp  = (const float*)d_in[3];   // [6,64,32]
    const float* asp  = (const float*)d_in[4];   // [6,64]
    const float* Wint = (const float*)d_in[5];   // [2,64,32]
    const float* aint = (const float*)d_in[6];   // [2,64]
    const float* Wout = (const float*)d_in[7];   // [256,64]
    const float* aout = (const float*)d_in[8];   // [128]
    float* out = (float*)d_out;                  // [4096,64]

    float* ws    = (float*)d_ws;
    float* Wh_t  = ws;                    // [4096][256]  node-major
    float* src   = Wh_t + 1048576;        // [8][4096]
    float* dst_t = src  + 32768;          // [4096][8]
    float* Who   = dst_t + 32768;         // [4096][64]
    float* o1    = Who  + 262144;         // [4096]
    float* o2    = o1   + 4096;           // [4096]
    int*   col   = (int*)(o2 + 4096);     // [4096][128]
    int*   deg   = col + 4096 * MAXDEG;   // [4096]

    k_fused1  <<<N / NPB, 256, 0, stream>>>(x, ie, (const float4*)adj, Wsp, asp,
                                            Wint, aint, Wh_t, src, dst_t, col, deg);
    k_attn1who<<<N,       256, 0, stream>>>(col, deg, Wh_t, src, dst_t, Wout, aout,
                                            Who, o1, o2);
    k_attn2   <<<N / 4,   256, 0, stream>>>(col, deg, Who, o1, o2, out);
}

// Round 3
// 150.400 us; speedup vs baseline: 1.1323x; 1.0575x over previous
//
#include <hip/hip_runtime.h>

#define N      4096
#define NIN    64
#define NHID   32
#define NOUT   64
#define NHEADS 8
#define H_SP   6
#define D_INT  32
#define MAXDEG 128
#define NPB    4      // nodes per block in K1
#define ROWS   8      // rows per block in K2
#define ALPHA  0.2f

// popc(mask & lanemask_lt) — prefix population count for wave64 ballots
__device__ __forceinline__ int mbcnt64(unsigned long long m) {
    return __builtin_amdgcn_mbcnt_hi((unsigned)(m >> 32),
           __builtin_amdgcn_mbcnt_lo((unsigned)m, 0u));
}

// ---------------------------------------------------------------------------
// K1 (fused proj + csr), 4 nodes per block, 1024 blocks. (unchanged)
// ---------------------------------------------------------------------------
__global__ __launch_bounds__(256) void k_fused1(
    const float* __restrict__ x, const float* __restrict__ ie,
    const float4* __restrict__ adj4,
    const float* __restrict__ Wsp, const float* __restrict__ asp,
    const float* __restrict__ Wint, const float* __restrict__ aint,
    float* __restrict__ Wh_t, float* __restrict__ src, float* __restrict__ dst_t,
    int* __restrict__ col, int* __restrict__ deg)
{
    const int nb   = blockIdx.x * NPB;
    const int tid  = threadIdx.x;
    const int wv   = tid >> 6, lane = tid & 63;
    const int h    = tid >> 5, f    = tid & 31;

    __shared__ float xs_t[NIN][NPB];     // transposed x tile: [col][node]
    __shared__ float ies[NPB][D_INT];

    xs_t[tid & 63][tid >> 6] = x[nb * NIN + tid];
    if (tid < NPB * D_INT) ies[tid >> 5][tid & 31] = ie[nb * D_INT + tid];
    __syncthreads();

    const float* W = (h < H_SP) ? (Wsp + h * NIN * NHID)
                                : (Wint + (h - H_SP) * NIN * NHID);
    float acc[NPB] = {0.f, 0.f, 0.f, 0.f};
#pragma unroll
    for (int c = 0; c < NIN; ++c) {
        const float wval = W[c * NHID + f];
        const float4 xv  = *(const float4*)&xs_t[c][0];   // broadcast b128
        acc[0] += xv.x * wval; acc[1] += xv.y * wval;
        acc[2] += xv.z * wval; acc[3] += xv.w * wval;
    }
#pragma unroll
    for (int m = 0; m < NPB; ++m)
        Wh_t[(size_t)(nb + m) * 256 + tid] = acc[m];   // coalesced 1 KB stores

    const float a1v = (h < H_SP) ? asp[h * 64 + f]      : aint[(h - H_SP) * 64 + f];
    const float a2v = (h < H_SP) ? asp[h * 64 + 32 + f] : aint[(h - H_SP) * 64 + 32 + f];
#pragma unroll
    for (int m = 0; m < NPB; ++m) {
        const float b = (h < H_SP) ? acc[m] : ies[m][f];
        float s1 = b * a1v, s2 = b * a2v;
#pragma unroll
        for (int mm = 16; mm >= 1; mm >>= 1) {
            s1 += __shfl_xor(s1, mm);
            s2 += __shfl_xor(s2, mm);
        }
        if (f == 0) { src[h * N + nb + m] = s1; dst_t[(nb + m) * 8 + h] = s2; }
    }

    // --- csr: wave wv compacts row nb+wv via ballots ---
    const int r = nb + wv;
    const float4* row = adj4 + (size_t)r * (N / 4);
    int cnt = 0;
#pragma unroll 4
    for (int t = 0; t < 16; ++t) {
        float4 v = row[t * 64 + lane];
        unsigned long long bx = __ballot(v.x > 0.f);
        unsigned long long by = __ballot(v.y > 0.f);
        unsigned long long bz = __ballot(v.z > 0.f);
        unsigned long long bw = __ballot(v.w > 0.f);
        const int tx = __popcll(bx), ty = __popcll(by);
        const int tz = __popcll(bz), tw = __popcll(bw);
        const int idx0 = (t * 64 + lane) * 4;
        const int px = cnt + mbcnt64(bx);
        const int py = cnt + tx + mbcnt64(by);
        const int pz = cnt + tx + ty + mbcnt64(bz);
        const int pw = cnt + tx + ty + tz + mbcnt64(bw);
        if (v.x > 0.f && px < MAXDEG) col[r * MAXDEG + px] = idx0;
        if (v.y > 0.f && py < MAXDEG) col[r * MAXDEG + py] = idx0 + 1;
        if (v.z > 0.f && pz < MAXDEG) col[r * MAXDEG + pz] = idx0 + 2;
        if (v.w > 0.f && pw < MAXDEG) col[r * MAXDEG + pw] = idx0 + 3;
        cnt += tx + ty + tz + tw;
    }
    if (lane == 0) deg[r] = (cnt < MAXDEG) ? cnt : MAXDEG;
}

// ---------------------------------------------------------------------------
// K2 (fused attn1 + Who): 8 rows per 512-thread block, 512 blocks (= 2/CU,
// all resident in one round). TA-line economy:
//  - wave-per-row softmax: 1 lane loads ALL 8 heads of a neighbor (32 B
//    float4 pair) -> ~84 lines/row vs 336.
//  - wave-per-row gather: neighbor row read exactly once (672 lines/row,
//    optimal); weights via permuted-[h0][p] LDS so each lane's 4 head
//    weights are ONE broadcast ds_read_b128.
//  - Wout read ONCE per block via disjoint per-wave 32-row register slices
//    (268 MB -> 32 MB total; 1024 -> 128 lines/row).
//  - 2 barriers total; part[] overlays dead w[] LDS.
// ---------------------------------------------------------------------------
__global__ __launch_bounds__(512, 4) void k_attn1who(
    const int* __restrict__ col, const int* __restrict__ deg,
    const float* __restrict__ Wh_t, const float* __restrict__ src,
    const float* __restrict__ dst_t, const float* __restrict__ Wout,
    const float* __restrict__ aout,
    float* __restrict__ Who, float* __restrict__ o1, float* __restrict__ o2)
{
    const int r0   = blockIdx.x * ROWS;
    const int tid  = threadIdx.x;
    const int wv   = tid >> 6, lane = tid & 63;
    const int r    = r0 + wv;                    // wave wv owns row r

    __shared__ __align__(16) int   cs[ROWS][MAXDEG];                 // 4 KB
    __shared__ __align__(16) float w_smem[ROWS * MAXDEG * NHEADS];   // 32 KB
    __shared__ __align__(16) float hs[ROWS][NHEADS * NHID];          // 8 KB

    // ---- phase 1 (wave-local): softmax for row r over all 8 heads ----
    const int d  = deg[r];
    const int j0 = (lane < d)      ? col[r * MAXDEG + lane]      : 0;
    const int j1 = (lane + 64 < d) ? col[r * MAXDEG + 64 + lane] : 0;
    cs[wv][lane]      = (lane < d)      ? j0 : 0;
    cs[wv][lane + 64] = (lane + 64 < d) ? j1 : 0;

    float sr[NHEADS];
#pragma unroll
    for (int h = 0; h < NHEADS; ++h) sr[h] = src[h * N + r];   // wave-uniform

    float dA[NHEADS] = {}, dB[NHEADS] = {};
    if (lane < d) {
        *(float4*)&dA[0] = *(const float4*)&dst_t[j0 * 8];
        *(float4*)&dA[4] = *(const float4*)&dst_t[j0 * 8 + 4];
    }
    if (lane + 64 < d) {
        *(float4*)&dB[0] = *(const float4*)&dst_t[j1 * 8];
        *(float4*)&dB[4] = *(const float4*)&dst_t[j1 * 8 + 4];
    }

    float eA[NHEADS], eB[NHEADS], mx[NHEADS];
#pragma unroll
    for (int h = 0; h < NHEADS; ++h) {
        float a = sr[h] + dA[h]; a = a > 0.f ? a : ALPHA * a;
        float b = sr[h] + dB[h]; b = b > 0.f ? b : ALPHA * b;
        eA[h] = (lane < d)      ? a : -3.4e38f;
        eB[h] = (lane + 64 < d) ? b : -3.4e38f;
        mx[h] = fmaxf(eA[h], eB[h]);
    }
#pragma unroll
    for (int m = 32; m >= 1; m >>= 1)
#pragma unroll
        for (int h = 0; h < NHEADS; ++h) mx[h] = fmaxf(mx[h], __shfl_xor(mx[h], m));

    float pA[NHEADS], pB[NHEADS], sum[NHEADS];
#pragma unroll
    for (int h = 0; h < NHEADS; ++h) {
        pA[h] = (lane < d)      ? __expf(eA[h] - mx[h]) : 0.f;
        pB[h] = (lane + 64 < d) ? __expf(eB[h] - mx[h]) : 0.f;
        sum[h] = pA[h] + pB[h];
    }
#pragma unroll
    for (int m = 32; m >= 1; m >>= 1)
#pragma unroll
        for (int h = 0; h < NHEADS; ++h) sum[h] += __shfl_xor(sum[h], m);

    // permuted store: w_smem[(wv*128+k)*8 + h0*4 + p] = weight of head (2p+h0)
    {
        float inv[NHEADS];
#pragma unroll
        for (int h = 0; h < NHEADS; ++h) inv[h] = 1.f / sum[h];
        float* wa = &w_smem[(wv * MAXDEG + lane) * 8];
        *(float4*)&wa[0] = make_float4(pA[0]*inv[0], pA[2]*inv[2], pA[4]*inv[4], pA[6]*inv[6]);
        *(float4*)&wa[4] = make_float4(pA[1]*inv[1], pA[3]*inv[3], pA[5]*inv[5], pA[7]*inv[7]);
        float* wb = &w_smem[(wv * MAXDEG + lane + 64) * 8];
        *(float4*)&wb[0] = make_float4(pB[0]*inv[0], pB[2]*inv[2], pB[4]*inv[4], pB[6]*inv[6]);
        *(float4*)&wb[4] = make_float4(pB[1]*inv[1], pB[3]*inv[3], pB[5]*inv[5], pB[7]*inv[7]);
    }

    // ---- phase 2 (wave-local): gather row r, full 256 features per wave ----
    // acc_p covers feature f = p*64+lane (head 2p + (lane>>5)); weight = one
    // broadcast b128 at w_smem[(wv*128+k)*8 + (lane>>5)*4].
    const int d4 = (d + 3) & ~3;
    const float* wrow = &w_smem[wv * MAXDEG * 8 + (lane >> 5) * 4];
    const int*   csr_ = &cs[wv][0];
    float a0 = 0.f, a1 = 0.f, a2 = 0.f, a3 = 0.f;
    for (int k = 0; k < d4; k += 4) {
        const int4 jj = *(const int4*)&csr_[k];            // uniform broadcast
        const float* p0 = Wh_t + (size_t)jj.x * 256 + lane;
        const float* p1 = Wh_t + (size_t)jj.y * 256 + lane;
        const float* p2 = Wh_t + (size_t)jj.z * 256 + lane;
        const float* p3 = Wh_t + (size_t)jj.w * 256 + lane;
        const float g00 = p0[0], g01 = p0[64], g02 = p0[128], g03 = p0[192];
        const float g10 = p1[0], g11 = p1[64], g12 = p1[128], g13 = p1[192];
        const float g20 = p2[0], g21 = p2[64], g22 = p2[128], g23 = p2[192];
        const float g30 = p3[0], g31 = p3[64], g32 = p3[128], g33 = p3[192];
        const float4 w0 = *(const float4*)&wrow[(k + 0) * 8];
        const float4 w1 = *(const float4*)&wrow[(k + 1) * 8];
        const float4 w2 = *(const float4*)&wrow[(k + 2) * 8];
        const float4 w3 = *(const float4*)&wrow[(k + 3) * 8];
        a0 += w0.x * g00 + w1.x * g10 + w2.x * g20 + w3.x * g30;
        a1 += w0.y * g01 + w1.y * g11 + w2.y * g21 + w3.y * g31;
        a2 += w0.z * g02 + w1.z * g12 + w2.z * g22 + w3.z * g32;
        a3 += w0.w * g03 + w1.w * g13 + w2.w * g23 + w3.w * g33;
    }
    a0 = a0 > 0.f ? a0 : __expf(a0) - 1.f;   // elu (concat heads)
    a1 = a1 > 0.f ? a1 : __expf(a1) - 1.f;
    a2 = a2 > 0.f ? a2 : __expf(a2) - 1.f;
    a3 = a3 > 0.f ? a3 : __expf(a3) - 1.f;
    hs[wv][lane]       = a0;
    hs[wv][lane + 64]  = a1;
    hs[wv][lane + 128] = a2;
    hs[wv][lane + 192] = a3;
    __syncthreads();    // hs cross-wave; also all w_smem reads done (overlay)

    // ---- phase 3: Who = h @ Wout; wave wv owns c-slice [wv*32, wv*32+32) ----
    float* part = w_smem;                     // [8 waves][8 rows][64] overlay
    {
        float wreg[32];
#pragma unroll
        for (int cc = 0; cc < 32; ++cc)
            wreg[cc] = Wout[(wv * 32 + cc) * NOUT + lane];
#pragma unroll
        for (int m = 0; m < ROWS; ++m) {
            float acc = 0.f;
#pragma unroll
            for (int cc = 0; cc < 32; cc += 4) {
                const float4 hv = *(const float4*)&hs[m][wv * 32 + cc];  // uniform
                acc += hv.x * wreg[cc]     + hv.y * wreg[cc + 1]
                     + hv.z * wreg[cc + 2] + hv.w * wreg[cc + 3];
            }
            part[(wv * ROWS + m) * NOUT + lane] = acc;
        }
    }
    __syncthreads();

    // ---- phase 4: wave wv finalizes row r ----
    float who = 0.f;
#pragma unroll
    for (int q = 0; q < 8; ++q) who += part[(q * ROWS + wv) * NOUT + lane];
    Who[(size_t)r * NOUT + lane] = who;
    float v1 = who * aout[lane];
    float v2 = who * aout[NOUT + lane];
#pragma unroll
    for (int m = 32; m >= 1; m >>= 1) {
        v1 += __shfl_xor(v1, m);
        v2 += __shfl_xor(v2, m);
    }
    if (lane == 0) { o1[r] = v1; o2[r] = v2; }
}

// ---------------------------------------------------------------------------
// K3 (attn2): wave-per-row, sync-free, no LDS. (unchanged)
// ---------------------------------------------------------------------------
__global__ __launch_bounds__(256) void k_attn2(
    const int* __restrict__ col, const int* __restrict__ deg,
    const float* __restrict__ Who, const float* __restrict__ o1,
    const float* __restrict__ o2, float* __restrict__ out)
{
    const int tid  = threadIdx.x;
    const int wv   = tid >> 6, lane = tid & 63;
    const int r    = blockIdx.x * 4 + wv;

    const int d  = deg[r];
    const int j0 = (lane < d)      ? col[r * MAXDEG + lane]      : 0;
    const int j1 = (lane + 64 < d) ? col[r * MAXDEG + 64 + lane] : 0;
    const float sr = o1[r];

    float e0 = -3.4e38f, e1 = -3.4e38f;
    if (lane < d)      { float e = sr + o2[j0]; e0 = e > 0.f ? e : ALPHA * e; }
    if (lane + 64 < d) { float e = sr + o2[j1]; e1 = e > 0.f ? e : ALPHA * e; }
    float mx = fmaxf(e0, e1);
#pragma unroll
    for (int m = 32; m >= 1; m >>= 1) mx = fmaxf(mx, __shfl_xor(mx, m));
    float p0 = (lane < d)      ? __expf(e0 - mx) : 0.f;
    float p1 = (lane + 64 < d) ? __expf(e1 - mx) : 0.f;
    float s = p0 + p1;
#pragma unroll
    for (int m = 32; m >= 1; m >>= 1) s += __shfl_xor(s, m);
    const float inv = 1.f / s;
    const float w0 = p0 * inv, w1 = p1 * inv;

    float acc = 0.f;
    const int dlo = d < 64 ? d : 64;
#pragma unroll 4
    for (int k = 0; k < dlo; ++k) {
        const int   j  = __builtin_amdgcn_readlane(j0, k);
        const float wt = __uint_as_float(
            __builtin_amdgcn_readlane(__float_as_uint(w0), k));
        acc += wt * Who[(size_t)j * NOUT + lane];
    }
#pragma unroll 2
    for (int k = 64; k < d; ++k) {
        const int   j  = __builtin_amdgcn_readlane(j1, k - 64);
        const float wt = __uint_as_float(
            __builtin_amdgcn_readlane(__float_as_uint(w1), k - 64));
        acc += wt * Who[(size_t)j * NOUT + lane];
    }
    out[(size_t)r * NOUT + lane] = tanhf(acc);
}

// ---------------------------------------------------------------------------
extern "C" void kernel_launch(void* const* d_in, const int* in_sizes, int n_in,
                              void* d_out, int out_size, void* d_ws, size_t ws_size,
                              hipStream_t stream) {
    const float* x    = (const float*)d_in[0];   // [4096,64]
    const float* adj  = (const float*)d_in[1];   // [4096,4096]
    const float* ie   = (const float*)d_in[2];   // [4096,32]
    const float* Wsp  = (const float*)d_in[3];   // [6,64,32]
    const float* asp  = (const float*)d_in[4];   // [6,64]
    const float* Wint = (const float*)d_in[5];   // [2,64,32]
    const float* aint = (const float*)d_in[6];   // [2,64]
    const float* Wout = (const float*)d_in[7];   // [256,64]
    const float* aout = (const float*)d_in[8];   // [128]
    float* out = (float*)d_out;                  // [4096,64]

    float* ws    = (float*)d_ws;
    float* Wh_t  = ws;                    // [4096][256]  node-major
    float* src   = Wh_t + 1048576;        // [8][4096]
    float* dst_t = src  + 32768;          // [4096][8]
    float* Who   = dst_t + 32768;         // [4096][64]
    float* o1    = Who  + 262144;         // [4096]
    float* o2    = o1   + 4096;           // [4096]
    int*   col   = (int*)(o2 + 4096);     // [4096][128]
    int*   deg   = col + 4096 * MAXDEG;   // [4096]

    k_fused1  <<<N / NPB,  256, 0, stream>>>(x, ie, (const float4*)adj, Wsp, asp,
                                             Wint, aint, Wh_t, src, dst_t, col, deg);
    k_attn1who<<<N / ROWS, 512, 0, stream>>>(col, deg, Wh_t, src, dst_t, Wout, aout,
                                             Who, o1, o2);
    k_attn2   <<<N / 4,    256, 0, stream>>>(col, deg, Who, o1, o2, out);
}

// Round 4
// 141.542 us; speedup vs baseline: 1.2032x; 1.0626x over previous
//
#include <hip/hip_runtime.h>

#define N      4096
#define NIN    64
#define NHID   32
#define NOUT   64
#define NHEADS 8
#define H_SP   6
#define D_INT  32
#define MAXDEG 128
#define NPB    4      // nodes per block in K1
#define ROWS   8      // rows per block in K2
#define WPAD   (MAXDEG + 4)   // +16B so the 8 head-rows hit distinct banks
#define ALPHA  0.2f

// popc(mask & lanemask_lt) — prefix population count for wave64 ballots
__device__ __forceinline__ int mbcnt64(unsigned long long m) {
    return __builtin_amdgcn_mbcnt_hi((unsigned)(m >> 32),
           __builtin_amdgcn_mbcnt_lo((unsigned)m, 0u));
}

// ---------------------------------------------------------------------------
// K1 (fused proj + csr), 4 nodes per block, 1024 blocks. (unchanged)
// ---------------------------------------------------------------------------
__global__ __launch_bounds__(256) void k_fused1(
    const float* __restrict__ x, const float* __restrict__ ie,
    const float4* __restrict__ adj4,
    const float* __restrict__ Wsp, const float* __restrict__ asp,
    const float* __restrict__ Wint, const float* __restrict__ aint,
    float* __restrict__ Wh_t, float* __restrict__ src, float* __restrict__ dst_t,
    int* __restrict__ col, int* __restrict__ deg)
{
    const int nb   = blockIdx.x * NPB;
    const int tid  = threadIdx.x;
    const int wv   = tid >> 6, lane = tid & 63;
    const int h    = tid >> 5, f    = tid & 31;

    __shared__ float xs_t[NIN][NPB];     // transposed x tile: [col][node]
    __shared__ float ies[NPB][D_INT];

    xs_t[tid & 63][tid >> 6] = x[nb * NIN + tid];
    if (tid < NPB * D_INT) ies[tid >> 5][tid & 31] = ie[nb * D_INT + tid];
    __syncthreads();

    const float* W = (h < H_SP) ? (Wsp + h * NIN * NHID)
                                : (Wint + (h - H_SP) * NIN * NHID);
    float acc[NPB] = {0.f, 0.f, 0.f, 0.f};
#pragma unroll
    for (int c = 0; c < NIN; ++c) {
        const float wval = W[c * NHID + f];
        const float4 xv  = *(const float4*)&xs_t[c][0];   // broadcast b128
        acc[0] += xv.x * wval; acc[1] += xv.y * wval;
        acc[2] += xv.z * wval; acc[3] += xv.w * wval;
    }
#pragma unroll
    for (int m = 0; m < NPB; ++m)
        Wh_t[(size_t)(nb + m) * 256 + tid] = acc[m];   // coalesced 1 KB stores

    const float a1v = (h < H_SP) ? asp[h * 64 + f]      : aint[(h - H_SP) * 64 + f];
    const float a2v = (h < H_SP) ? asp[h * 64 + 32 + f] : aint[(h - H_SP) * 64 + 32 + f];
#pragma unroll
    for (int m = 0; m < NPB; ++m) {
        const float b = (h < H_SP) ? acc[m] : ies[m][f];
        float s1 = b * a1v, s2 = b * a2v;
#pragma unroll
        for (int mm = 16; mm >= 1; mm >>= 1) {
            s1 += __shfl_xor(s1, mm);
            s2 += __shfl_xor(s2, mm);
        }
        if (f == 0) { src[h * N + nb + m] = s1; dst_t[(nb + m) * 8 + h] = s2; }
    }

    // --- csr: wave wv compacts row nb+wv via ballots ---
    const int r = nb + wv;
    const float4* row = adj4 + (size_t)r * (N / 4);
    int cnt = 0;
#pragma unroll 4
    for (int t = 0; t < 16; ++t) {
        float4 v = row[t * 64 + lane];
        unsigned long long bx = __ballot(v.x > 0.f);
        unsigned long long by = __ballot(v.y > 0.f);
        unsigned long long bz = __ballot(v.z > 0.f);
        unsigned long long bw = __ballot(v.w > 0.f);
        const int tx = __popcll(bx), ty = __popcll(by);
        const int tz = __popcll(bz), tw = __popcll(bw);
        const int idx0 = (t * 64 + lane) * 4;
        const int px = cnt + mbcnt64(bx);
        const int py = cnt + tx + mbcnt64(by);
        const int pz = cnt + tx + ty + mbcnt64(bz);
        const int pw = cnt + tx + ty + tz + mbcnt64(bw);
        if (v.x > 0.f && px < MAXDEG) col[r * MAXDEG + px] = idx0;
        if (v.y > 0.f && py < MAXDEG) col[r * MAXDEG + py] = idx0 + 1;
        if (v.z > 0.f && pz < MAXDEG) col[r * MAXDEG + pz] = idx0 + 2;
        if (v.w > 0.f && pw < MAXDEG) col[r * MAXDEG + pw] = idx0 + 3;
        cnt += tx + ty + tz + tw;
    }
    if (lane == 0) deg[r] = (cnt < MAXDEG) ? cnt : MAXDEG;
}

// ---------------------------------------------------------------------------
// K2 (fused attn1 + Who): 8 rows per 512-thread block, 512 blocks.
// VMEM-instruction economy in the gather:
//  - element e = head*32+hid, so float4 @ 4*lane keeps one HEAD per lane ->
//    ONE global_load_dwordx4 per neighbor row (was 4 dword loads).
//  - weights LDS transposed [row][head][k] (+pad): the lane's 4 neighbor
//    weights = one broadcast ds_read_b128; head rows on distinct banks.
//  - Wout read once per block via per-wave 32-row register slices.
// ---------------------------------------------------------------------------
__global__ __launch_bounds__(512, 4) void k_attn1who(
    const int* __restrict__ col, const int* __restrict__ deg,
    const float* __restrict__ Wh_t, const float* __restrict__ src,
    const float* __restrict__ dst_t, const float* __restrict__ Wout,
    const float* __restrict__ aout,
    float* __restrict__ Who, float* __restrict__ o1, float* __restrict__ o2)
{
    const int r0   = blockIdx.x * ROWS;
    const int tid  = threadIdx.x;
    const int wv   = tid >> 6, lane = tid & 63;
    const int r    = r0 + wv;                    // wave wv owns row r

    __shared__ __align__(16) int   cs[ROWS][MAXDEG];            // 4 KB
    __shared__ __align__(16) float w_t[ROWS][NHEADS][WPAD];     // 33 KB
    __shared__ __align__(16) float hs[ROWS][NHEADS * NHID];     // 8 KB

    // ---- phase 1 (wave-local): softmax for row r over all 8 heads ----
    const int d  = deg[r];
    const int j0 = (lane < d)      ? col[r * MAXDEG + lane]      : 0;
    const int j1 = (lane + 64 < d) ? col[r * MAXDEG + 64 + lane] : 0;
    cs[wv][lane]      = j0;
    cs[wv][lane + 64] = j1;

    float sr[NHEADS];
#pragma unroll
    for (int h = 0; h < NHEADS; ++h) sr[h] = src[h * N + r];   // wave-uniform

    float dA[NHEADS] = {}, dB[NHEADS] = {};
    if (lane < d) {
        *(float4*)&dA[0] = *(const float4*)&dst_t[j0 * 8];
        *(float4*)&dA[4] = *(const float4*)&dst_t[j0 * 8 + 4];
    }
    if (lane + 64 < d) {
        *(float4*)&dB[0] = *(const float4*)&dst_t[j1 * 8];
        *(float4*)&dB[4] = *(const float4*)&dst_t[j1 * 8 + 4];
    }

    float eA[NHEADS], eB[NHEADS], mx[NHEADS];
#pragma unroll
    for (int h = 0; h < NHEADS; ++h) {
        float a = sr[h] + dA[h]; a = a > 0.f ? a : ALPHA * a;
        float b = sr[h] + dB[h]; b = b > 0.f ? b : ALPHA * b;
        eA[h] = (lane < d)      ? a : -3.4e38f;
        eB[h] = (lane + 64 < d) ? b : -3.4e38f;
        mx[h] = fmaxf(eA[h], eB[h]);
    }
#pragma unroll
    for (int m = 32; m >= 1; m >>= 1)
#pragma unroll
        for (int h = 0; h < NHEADS; ++h) mx[h] = fmaxf(mx[h], __shfl_xor(mx[h], m));

    float pA[NHEADS], pB[NHEADS], sum[NHEADS];
#pragma unroll
    for (int h = 0; h < NHEADS; ++h) {
        pA[h] = (lane < d)      ? __expf(eA[h] - mx[h]) : 0.f;
        pB[h] = (lane + 64 < d) ? __expf(eB[h] - mx[h]) : 0.f;
        sum[h] = pA[h] + pB[h];
    }
#pragma unroll
    for (int m = 32; m >= 1; m >>= 1)
#pragma unroll
        for (int h = 0; h < NHEADS; ++h) sum[h] += __shfl_xor(sum[h], m);

    // transposed store: w_t[wv][h][k] (lane-consecutive, conflict-free)
#pragma unroll
    for (int h = 0; h < NHEADS; ++h) {
        const float inv = 1.f / sum[h];
        w_t[wv][h][lane]      = pA[h] * inv;   // 0 beyond d
        w_t[wv][h][lane + 64] = pB[h] * inv;
    }

    // ---- phase 2 (wave-local): gather row r; 1 dwordx4 per neighbor ----
    // lane covers elements 4*lane..4*lane+3, all in head (lane>>3).
    const float* wrow = &w_t[wv][lane >> 3][0];
    const int*   csr_ = &cs[wv][0];
    float4 acc = make_float4(0.f, 0.f, 0.f, 0.f);
    const int d4 = (d + 3) & ~3;
    for (int k = 0; k < d4; k += 4) {
        const int4   jj = *(const int4*)&csr_[k];        // uniform broadcast
        const float4 wq = *(const float4*)&wrow[k];      // 4 neighbor weights
        const float4 ga = *(const float4*)&Wh_t[(size_t)jj.x * 256 + 4 * lane];
        const float4 gb = *(const float4*)&Wh_t[(size_t)jj.y * 256 + 4 * lane];
        const float4 gc = *(const float4*)&Wh_t[(size_t)jj.z * 256 + 4 * lane];
        const float4 gd = *(const float4*)&Wh_t[(size_t)jj.w * 256 + 4 * lane];
        acc.x += wq.x * ga.x + wq.y * gb.x + wq.z * gc.x + wq.w * gd.x;
        acc.y += wq.x * ga.y + wq.y * gb.y + wq.z * gc.y + wq.w * gd.y;
        acc.z += wq.x * ga.z + wq.y * gb.z + wq.z * gc.z + wq.w * gd.z;
        acc.w += wq.x * ga.w + wq.y * gb.w + wq.z * gc.w + wq.w * gd.w;
    }
    acc.x = acc.x > 0.f ? acc.x : __expf(acc.x) - 1.f;   // elu (concat heads)
    acc.y = acc.y > 0.f ? acc.y : __expf(acc.y) - 1.f;
    acc.z = acc.z > 0.f ? acc.z : __expf(acc.z) - 1.f;
    acc.w = acc.w > 0.f ? acc.w : __expf(acc.w) - 1.f;
    *(float4*)&hs[wv][4 * lane] = acc;                   // hs[wv][e] = elem e
    __syncthreads();    // hs cross-wave; all w_t reads done (overlay next)

    // ---- phase 3: Who = h @ Wout; wave wv owns c-slice [wv*32, wv*32+32) ----
    float* part = &w_t[0][0][0];              // [8 waves][8 rows][64] overlay
    {
        float wreg[32];
#pragma unroll
        for (int cc = 0; cc < 32; ++cc)
            wreg[cc] = Wout[(wv * 32 + cc) * NOUT + lane];
#pragma unroll
        for (int m = 0; m < ROWS; ++m) {
            float a = 0.f;
#pragma unroll
            for (int cc = 0; cc < 32; cc += 4) {
                const float4 hv = *(const float4*)&hs[m][wv * 32 + cc];  // uniform
                a += hv.x * wreg[cc]     + hv.y * wreg[cc + 1]
                   + hv.z * wreg[cc + 2] + hv.w * wreg[cc + 3];
            }
            part[(wv * ROWS + m) * NOUT + lane] = a;
        }
    }
    __syncthreads();

    // ---- phase 4: wave wv finalizes row r ----
    float who = 0.f;
#pragma unroll
    for (int q = 0; q < 8; ++q) who += part[(q * ROWS + wv) * NOUT + lane];
    Who[(size_t)r * NOUT + lane] = who;
    float v1 = who * aout[lane];
    float v2 = who * aout[NOUT + lane];
#pragma unroll
    for (int m = 32; m >= 1; m >>= 1) {
        v1 += __shfl_xor(v1, m);
        v2 += __shfl_xor(v2, m);
    }
    if (lane == 0) { o1[r] = v1; o2[r] = v2; }
}

// ---------------------------------------------------------------------------
// K3 (attn2): wave-per-row, sync-free, no LDS. 4 neighbors per iteration:
// lane = sub*16 + q handles neighbor k+sub, features 4q..4q+3 (float4) ->
// VMEM instrs /4; (j,w) redistributed via __shfl; xor-16/32 folds sub-partials.
// ---------------------------------------------------------------------------
__global__ __launch_bounds__(256) void k_attn2(
    const int* __restrict__ col, const int* __restrict__ deg,
    const float* __restrict__ Who, const float* __restrict__ o1,
    const float* __restrict__ o2, float* __restrict__ out)
{
    const int tid  = threadIdx.x;
    const int wv   = tid >> 6, lane = tid & 63;
    const int r    = blockIdx.x * 4 + wv;

    const int d  = deg[r];
    const int j0 = (lane < d)      ? col[r * MAXDEG + lane]      : 0;
    const int j1 = (lane + 64 < d) ? col[r * MAXDEG + 64 + lane] : 0;
    const float sr = o1[r];

    float e0 = -3.4e38f, e1 = -3.4e38f;
    if (lane < d)      { float e = sr + o2[j0]; e0 = e > 0.f ? e : ALPHA * e; }
    if (lane + 64 < d) { float e = sr + o2[j1]; e1 = e > 0.f ? e : ALPHA * e; }
    float mx = fmaxf(e0, e1);
#pragma unroll
    for (int m = 32; m >= 1; m >>= 1) mx = fmaxf(mx, __shfl_xor(mx, m));
    float p0 = (lane < d)      ? __expf(e0 - mx) : 0.f;
    float p1 = (lane + 64 < d) ? __expf(e1 - mx) : 0.f;
    float s = p0 + p1;
#pragma unroll
    for (int m = 32; m >= 1; m >>= 1) s += __shfl_xor(s, m);
    const float inv = 1.f / s;
    const float w0 = p0 * inv, w1 = p1 * inv;   // zero-padded beyond d

    const int sub = lane >> 4, q = lane & 15;
    float4 acc = make_float4(0.f, 0.f, 0.f, 0.f);
    const int dlo  = d < 64 ? d : 64;
    const int d4a  = (dlo + 3) & ~3;
#pragma unroll 2
    for (int k = 0; k < d4a; k += 4) {
        const int   jj = __shfl(j0, k + sub);
        const float ww = __shfl(w0, k + sub);
        const float4 g = *(const float4*)&Who[(size_t)jj * NOUT + 4 * q];
        acc.x += ww * g.x; acc.y += ww * g.y;
        acc.z += ww * g.z; acc.w += ww * g.w;
    }
    const int d4b = (d + 3) & ~3;
    for (int k = 64; k < d4b; k += 4) {
        const int   jj = __shfl(j1, (k - 64) + sub);
        const float ww = __shfl(w1, (k - 64) + sub);
        const float4 g = *(const float4*)&Who[(size_t)jj * NOUT + 4 * q];
        acc.x += ww * g.x; acc.y += ww * g.y;
        acc.z += ww * g.z; acc.w += ww * g.w;
    }
    // fold the 4 sub-group partials (lanes xor 16, 32)
#pragma unroll
    for (int m = 16; m <= 32; m <<= 1) {
        acc.x += __shfl_xor(acc.x, m);
        acc.y += __shfl_xor(acc.y, m);
        acc.z += __shfl_xor(acc.z, m);
        acc.w += __shfl_xor(acc.w, m);
    }
    if (lane < 16) {
        float4 o;
        o.x = tanhf(acc.x); o.y = tanhf(acc.y);
        o.z = tanhf(acc.z); o.w = tanhf(acc.w);
        *(float4*)&out[(size_t)r * NOUT + 4 * lane] = o;
    }
}

// ---------------------------------------------------------------------------
extern "C" void kernel_launch(void* const* d_in, const int* in_sizes, int n_in,
                              void* d_out, int out_size, void* d_ws, size_t ws_size,
                              hipStream_t stream) {
    const float* x    = (const float*)d_in[0];   // [4096,64]
    const float* adj  = (const float*)d_in[1];   // [4096,4096]
    const float* ie   = (const float*)d_in[2];   // [4096,32]
    const float* Wsp  = (const float*)d_in[3];   // [6,64,32]
    const float* asp  = (const float*)d_in[4];   // [6,64]
    const float* Wint = (const float*)d_in[5];   // [2,64,32]
    const float* aint = (const float*)d_in[6];   // [2,64]
    const float* Wout = (const float*)d_in[7];   // [256,64]
    const float* aout = (const float*)d_in[8];   // [128]
    float* out = (float*)d_out;                  // [4096,64]

    float* ws    = (float*)d_ws;
    float* Wh_t  = ws;                    // [4096][256]  node-major
    float* src   = Wh_t + 1048576;        // [8][4096]
    float* dst_t = src  + 32768;          // [4096][8]
    float* Who   = dst_t + 32768;         // [4096][64]
    float* o1    = Who  + 262144;         // [4096]
    float* o2    = o1   + 4096;           // [4096]
    int*   col   = (int*)(o2 + 4096);     // [4096][128]
    int*   deg   = col + 4096 * MAXDEG;   // [4096]

    k_fused1  <<<N / NPB,  256, 0, stream>>>(x, ie, (const float4*)adj, Wsp, asp,
                                             Wint, aint, Wh_t, src, dst_t, col, deg);
    k_attn1who<<<N / ROWS, 512, 0, stream>>>(col, deg, Wh_t, src, dst_t, Wout, aout,
                                             Who, o1, o2);
    k_attn2   <<<N / 4,    256, 0, stream>>>(col, deg, Who, o1, o2, out);
}

// Round 5
// 141.274 us; speedup vs baseline: 1.2054x; 1.0019x over previous
//
#include <hip/hip_runtime.h>

#define N      4096
#define NIN    64
#define NHID   32
#define NOUT   64
#define NHEADS 8
#define H_SP   6
#define D_INT  32
#define MAXDEG 128
#define NPB    4      // nodes per block in K1
#define ROWS   8      // rows per block in K2
#define WPAD   (MAXDEG + 4)   // +16B so the 8 head-rows hit distinct banks
#define ALPHA  0.2f

// popc(mask & lanemask_lt) — prefix population count for wave64 ballots
__device__ __forceinline__ int mbcnt64(unsigned long long m) {
    return __builtin_amdgcn_mbcnt_hi((unsigned)(m >> 32),
           __builtin_amdgcn_mbcnt_lo((unsigned)m, 0u));
}

// ---------------------------------------------------------------------------
// K1 (fused proj + csr), 4 nodes per block, 1024 blocks. (unchanged)
// ---------------------------------------------------------------------------
__global__ __launch_bounds__(256) void k_fused1(
    const float* __restrict__ x, const float* __restrict__ ie,
    const float4* __restrict__ adj4,
    const float* __restrict__ Wsp, const float* __restrict__ asp,
    const float* __restrict__ Wint, const float* __restrict__ aint,
    float* __restrict__ Wh_t, float* __restrict__ src, float* __restrict__ dst_t,
    int* __restrict__ col, int* __restrict__ deg)
{
    const int nb   = blockIdx.x * NPB;
    const int tid  = threadIdx.x;
    const int wv   = tid >> 6, lane = tid & 63;
    const int h    = tid >> 5, f    = tid & 31;

    __shared__ float xs_t[NIN][NPB];     // transposed x tile: [col][node]
    __shared__ float ies[NPB][D_INT];

    xs_t[tid & 63][tid >> 6] = x[nb * NIN + tid];
    if (tid < NPB * D_INT) ies[tid >> 5][tid & 31] = ie[nb * D_INT + tid];
    __syncthreads();

    const float* W = (h < H_SP) ? (Wsp + h * NIN * NHID)
                                : (Wint + (h - H_SP) * NIN * NHID);
    float acc[NPB] = {0.f, 0.f, 0.f, 0.f};
#pragma unroll
    for (int c = 0; c < NIN; ++c) {
        const float wval = W[c * NHID + f];
        const float4 xv  = *(const float4*)&xs_t[c][0];   // broadcast b128
        acc[0] += xv.x * wval; acc[1] += xv.y * wval;
        acc[2] += xv.z * wval; acc[3] += xv.w * wval;
    }
#pragma unroll
    for (int m = 0; m < NPB; ++m)
        Wh_t[(size_t)(nb + m) * 256 + tid] = acc[m];   // coalesced 1 KB stores

    const float a1v = (h < H_SP) ? asp[h * 64 + f]      : aint[(h - H_SP) * 64 + f];
    const float a2v = (h < H_SP) ? asp[h * 64 + 32 + f] : aint[(h - H_SP) * 64 + 32 + f];
#pragma unroll
    for (int m = 0; m < NPB; ++m) {
        const float b = (h < H_SP) ? acc[m] : ies[m][f];
        float s1 = b * a1v, s2 = b * a2v;
#pragma unroll
        for (int mm = 16; mm >= 1; mm >>= 1) {
            s1 += __shfl_xor(s1, mm);
            s2 += __shfl_xor(s2, mm);
        }
        if (f == 0) { src[h * N + nb + m] = s1; dst_t[(nb + m) * 8 + h] = s2; }
    }

    // --- csr: wave wv compacts row nb+wv via ballots ---
    const int r = nb + wv;
    const float4* row = adj4 + (size_t)r * (N / 4);
    int cnt = 0;
#pragma unroll 4
    for (int t = 0; t < 16; ++t) {
        float4 v = row[t * 64 + lane];
        unsigned long long bx = __ballot(v.x > 0.f);
        unsigned long long by = __ballot(v.y > 0.f);
        unsigned long long bz = __ballot(v.z > 0.f);
        unsigned long long bw = __ballot(v.w > 0.f);
        const int tx = __popcll(bx), ty = __popcll(by);
        const int tz = __popcll(bz), tw = __popcll(bw);
        const int idx0 = (t * 64 + lane) * 4;
        const int px = cnt + mbcnt64(bx);
        const int py = cnt + tx + mbcnt64(by);
        const int pz = cnt + tx + ty + mbcnt64(bz);
        const int pw = cnt + tx + ty + tz + mbcnt64(bw);
        if (v.x > 0.f && px < MAXDEG) col[r * MAXDEG + px] = idx0;
        if (v.y > 0.f && py < MAXDEG) col[r * MAXDEG + py] = idx0 + 1;
        if (v.z > 0.f && pz < MAXDEG) col[r * MAXDEG + pz] = idx0 + 2;
        if (v.w > 0.f && pw < MAXDEG) col[r * MAXDEG + pw] = idx0 + 3;
        cnt += tx + ty + tz + tw;
    }
    if (lane == 0) deg[r] = (cnt < MAXDEG) ? cnt : MAXDEG;
}

// ---------------------------------------------------------------------------
// K2 (fused attn1 + Who): 8 rows per 512-thread block, 512 blocks.
// SHUFFLE-FREE softmax: no max-subtraction (shift-invariant; scores O(10),
// exp safe in f32), raw p stored to LDS; per-head denominator computed FOR
// FREE inside the gather (each lane reads every weight of its head anyway)
// and applied once to the accumulator. Phase 1 has ZERO cross-lane ops ->
// gather loads issue immediately.
// ---------------------------------------------------------------------------
__global__ __launch_bounds__(512, 4) void k_attn1who(
    const int* __restrict__ col, const int* __restrict__ deg,
    const float* __restrict__ Wh_t, const float* __restrict__ src,
    const float* __restrict__ dst_t, const float* __restrict__ Wout,
    const float* __restrict__ aout,
    float* __restrict__ Who, float* __restrict__ o1, float* __restrict__ o2)
{
    const int r0   = blockIdx.x * ROWS;
    const int tid  = threadIdx.x;
    const int wv   = tid >> 6, lane = tid & 63;
    const int r    = r0 + wv;                    // wave wv owns row r

    __shared__ __align__(16) int   cs[ROWS][MAXDEG];            // 4 KB
    __shared__ __align__(16) float w_t[ROWS][NHEADS][WPAD];     // 33 KB
    __shared__ __align__(16) float hs[ROWS][NHEADS * NHID];     // 8 KB

    // ---- phase 1 (wave-local, shuffle-free): raw exp weights for row r ----
    const int d  = deg[r];
    const int j0 = (lane < d)      ? col[r * MAXDEG + lane]      : 0;
    const int j1 = (lane + 64 < d) ? col[r * MAXDEG + 64 + lane] : 0;
    cs[wv][lane]      = j0;
    cs[wv][lane + 64] = j1;

    float sr[NHEADS];
#pragma unroll
    for (int h = 0; h < NHEADS; ++h) sr[h] = src[h * N + r];   // wave-uniform

    float dA[NHEADS] = {}, dB[NHEADS] = {};
    if (lane < d) {
        *(float4*)&dA[0] = *(const float4*)&dst_t[j0 * 8];
        *(float4*)&dA[4] = *(const float4*)&dst_t[j0 * 8 + 4];
    }
    if (lane + 64 < d) {
        *(float4*)&dB[0] = *(const float4*)&dst_t[j1 * 8];
        *(float4*)&dB[4] = *(const float4*)&dst_t[j1 * 8 + 4];
    }

#pragma unroll
    for (int h = 0; h < NHEADS; ++h) {
        float a = sr[h] + dA[h]; a = a > 0.f ? a : ALPHA * a;
        float b = sr[h] + dB[h]; b = b > 0.f ? b : ALPHA * b;
        w_t[wv][h][lane]      = (lane < d)      ? __expf(a) : 0.f;
        w_t[wv][h][lane + 64] = (lane + 64 < d) ? __expf(b) : 0.f;
    }

    // ---- phase 2 (wave-local): gather row r; denominator rides along ----
    // lane covers elements 4*lane..4*lane+3, all in head (lane>>3).
    const float* wrow = &w_t[wv][lane >> 3][0];
    const int*   csr_ = &cs[wv][0];
    float4 acc = make_float4(0.f, 0.f, 0.f, 0.f);
    float  ws  = 0.f;                                    // head denominator
    const int d4 = (d + 3) & ~3;
    for (int k = 0; k < d4; k += 4) {
        const int4   jj = *(const int4*)&csr_[k];        // uniform broadcast
        const float4 wq = *(const float4*)&wrow[k];      // 4 neighbor weights
        const float4 ga = *(const float4*)&Wh_t[(size_t)jj.x * 256 + 4 * lane];
        const float4 gb = *(const float4*)&Wh_t[(size_t)jj.y * 256 + 4 * lane];
        const float4 gc = *(const float4*)&Wh_t[(size_t)jj.z * 256 + 4 * lane];
        const float4 gd = *(const float4*)&Wh_t[(size_t)jj.w * 256 + 4 * lane];
        ws    += (wq.x + wq.y) + (wq.z + wq.w);
        acc.x += wq.x * ga.x + wq.y * gb.x + wq.z * gc.x + wq.w * gd.x;
        acc.y += wq.x * ga.y + wq.y * gb.y + wq.z * gc.y + wq.w * gd.y;
        acc.z += wq.x * ga.z + wq.y * gb.z + wq.z * gc.z + wq.w * gd.z;
        acc.w += wq.x * ga.w + wq.y * gb.w + wq.z * gc.w + wq.w * gd.w;
    }
    const float inv = 1.f / ws;
    acc.x *= inv; acc.y *= inv; acc.z *= inv; acc.w *= inv;
    acc.x = acc.x > 0.f ? acc.x : __expf(acc.x) - 1.f;   // elu (concat heads)
    acc.y = acc.y > 0.f ? acc.y : __expf(acc.y) - 1.f;
    acc.z = acc.z > 0.f ? acc.z : __expf(acc.z) - 1.f;
    acc.w = acc.w > 0.f ? acc.w : __expf(acc.w) - 1.f;
    *(float4*)&hs[wv][4 * lane] = acc;                   // hs[wv][e] = elem e
    __syncthreads();    // hs cross-wave; all w_t reads done (overlay next)

    // ---- phase 3: Who = h @ Wout; wave wv owns c-slice [wv*32, wv*32+32) ----
    float* part = &w_t[0][0][0];              // [8 waves][8 rows][64] overlay
    {
        float wreg[32];
#pragma unroll
        for (int cc = 0; cc < 32; ++cc)
            wreg[cc] = Wout[(wv * 32 + cc) * NOUT + lane];
#pragma unroll
        for (int m = 0; m < ROWS; ++m) {
            float a = 0.f;
#pragma unroll
            for (int cc = 0; cc < 32; cc += 4) {
                const float4 hv = *(const float4*)&hs[m][wv * 32 + cc];  // uniform
                a += hv.x * wreg[cc]     + hv.y * wreg[cc + 1]
                   + hv.z * wreg[cc + 2] + hv.w * wreg[cc + 3];
            }
            part[(wv * ROWS + m) * NOUT + lane] = a;
        }
    }
    __syncthreads();

    // ---- phase 4: wave wv finalizes row r ----
    float who = 0.f;
#pragma unroll
    for (int q = 0; q < 8; ++q) who += part[(q * ROWS + wv) * NOUT + lane];
    Who[(size_t)r * NOUT + lane] = who;
    float v1 = who * aout[lane];
    float v2 = who * aout[NOUT + lane];
#pragma unroll
    for (int m = 32; m >= 1; m >>= 1) {
        v1 += __shfl_xor(v1, m);
        v2 += __shfl_xor(v2, m);
    }
    if (lane == 0) { o1[r] = v1; o2[r] = v2; }
}

// ---------------------------------------------------------------------------
// K3 (attn2): wave-per-row, sync-free, no LDS. Shuffle-free softmax: raw
// exp weights (no max-sub, no sum reduce); the denominator accumulates
// alongside the gather and folds through the existing xor-16/32 reduction.
// ---------------------------------------------------------------------------
__global__ __launch_bounds__(256) void k_attn2(
    const int* __restrict__ col, const int* __restrict__ deg,
    const float* __restrict__ Who, const float* __restrict__ o1,
    const float* __restrict__ o2, float* __restrict__ out)
{
    const int tid  = threadIdx.x;
    const int wv   = tid >> 6, lane = tid & 63;
    const int r    = blockIdx.x * 4 + wv;

    const int d  = deg[r];
    const int j0 = (lane < d)      ? col[r * MAXDEG + lane]      : 0;
    const int j1 = (lane + 64 < d) ? col[r * MAXDEG + 64 + lane] : 0;
    const float sr = o1[r];

    float p0 = 0.f, p1 = 0.f;                     // raw exp weights, 0 padded
    if (lane < d) {
        float e = sr + o2[j0]; e = e > 0.f ? e : ALPHA * e;
        p0 = __expf(e);
    }
    if (lane + 64 < d) {
        float e = sr + o2[j1]; e = e > 0.f ? e : ALPHA * e;
        p1 = __expf(e);
    }

    const int sub = lane >> 4, q = lane & 15;
    float4 acc = make_float4(0.f, 0.f, 0.f, 0.f);
    float  sw  = 0.f;                             // denominator partial
    const int dlo  = d < 64 ? d : 64;
    const int d4a  = (dlo + 3) & ~3;
#pragma unroll 2
    for (int k = 0; k < d4a; k += 4) {
        const int   jj = __shfl(j0, k + sub);
        const float ww = __shfl(p0, k + sub);
        const float4 g = *(const float4*)&Who[(size_t)jj * NOUT + 4 * q];
        sw    += ww;
        acc.x += ww * g.x; acc.y += ww * g.y;
        acc.z += ww * g.z; acc.w += ww * g.w;
    }
    const int d4b = (d + 3) & ~3;
    for (int k = 64; k < d4b; k += 4) {
        const int   jj = __shfl(j1, (k - 64) + sub);
        const float ww = __shfl(p1, (k - 64) + sub);
        const float4 g = *(const float4*)&Who[(size_t)jj * NOUT + 4 * q];
        sw    += ww;
        acc.x += ww * g.x; acc.y += ww * g.y;
        acc.z += ww * g.z; acc.w += ww * g.w;
    }
    // fold the 4 sub-group partials (lanes xor 16, 32); sw rides along
#pragma unroll
    for (int m = 16; m <= 32; m <<= 1) {
        acc.x += __shfl_xor(acc.x, m);
        acc.y += __shfl_xor(acc.y, m);
        acc.z += __shfl_xor(acc.z, m);
        acc.w += __shfl_xor(acc.w, m);
        sw    += __shfl_xor(sw,    m);
    }
    if (lane < 16) {
        const float inv = 1.f / sw;
        float4 o;
        o.x = tanhf(acc.x * inv); o.y = tanhf(acc.y * inv);
        o.z = tanhf(acc.z * inv); o.w = tanhf(acc.w * inv);
        *(float4*)&out[(size_t)r * NOUT + 4 * lane] = o;
    }
}

// ---------------------------------------------------------------------------
extern "C" void kernel_launch(void* const* d_in, const int* in_sizes, int n_in,
                              void* d_out, int out_size, void* d_ws, size_t ws_size,
                              hipStream_t stream) {
    const float* x    = (const float*)d_in[0];   // [4096,64]
    const float* adj  = (const float*)d_in[1];   // [4096,4096]
    const float* ie   = (const float*)d_in[2];   // [4096,32]
    const float* Wsp  = (const float*)d_in[3];   // [6,64,32]
    const float* asp  = (const float*)d_in[4];   // [6,64]
    const float* Wint = (const float*)d_in[5];   // [2,64,32]
    const float* aint = (const float*)d_in[6];   // [2,64]
    const float* Wout = (const float*)d_in[7];   // [256,64]
    const float* aout = (const float*)d_in[8];   // [128]
    float* out = (float*)d_out;                  // [4096,64]

    float* ws    = (float*)d_ws;
    float* Wh_t  = ws;                    // [4096][256]  node-major
    float* src   = Wh_t + 1048576;        // [8][4096]
    float* dst_t = src  + 32768;          // [4096][8]
    float* Who   = dst_t + 32768;         // [4096][64]
    float* o1    = Who  + 262144;         // [4096]
    float* o2    = o1   + 4096;           // [4096]
    int*   col   = (int*)(o2 + 4096);     // [4096][128]
    int*   deg   = col + 4096 * MAXDEG;   // [4096]

    k_fused1  <<<N / NPB,  256, 0, stream>>>(x, ie, (const float4*)adj, Wsp, asp,
                                             Wint, aint, Wh_t, src, dst_t, col, deg);
    k_attn1who<<<N / ROWS, 512, 0, stream>>>(col, deg, Wh_t, src, dst_t, Wout, aout,
                                             Who, o1, o2);
    k_attn2   <<<N / 4,    256, 0, stream>>>(col, deg, Who, o1, o2, out);
}